// Round 8
// baseline (133.859 us; speedup 1.0000x reference)
//
#include <hip/hip_runtime.h>

#define BB  4
#define LL  512
#define HID 256
#define PAi 32
#define OO  64

using bf16x8 = __attribute__((ext_vector_type(8))) short;
using f32x4  = __attribute__((ext_vector_type(4))) float;

__device__ inline ushort f2bf(float x) {
    union { float f; unsigned u; } v; v.f = x;
    unsigned r = (v.u + 0x7fff + ((v.u >> 16) & 1)) >> 16;  // RNE
    return (ushort)r;
}

// -------- Kernel 1: h[b,l,p] = dot(hidden[b,l,:], W_in[p,:]) + b_in[p]; f32 + bf16 copies --------
__global__ __launch_bounds__(256) void k_in(const float* __restrict__ hidden,
                                            const float* __restrict__ W_in,
                                            const float* __restrict__ b_in,
                                            float* __restrict__ h,
                                            ushort* __restrict__ hb) {
    __shared__ float4 hid[8 * 64];
    const int tid  = threadIdx.x;
    const int row0 = blockIdx.x * 8;
    const float4* src = (const float4*)(hidden + (size_t)row0 * HID);
    hid[tid]       = src[tid];
    hid[tid + 256] = src[tid + 256];
    __syncthreads();
    const int p = tid & 31;
    const int r = tid >> 5;
    const float4* w = (const float4*)(W_in + (size_t)p * HID);
    float acc = 0.f;
#pragma unroll
    for (int k = 0; k < 64; ++k) {
        float4 hv = hid[r * 64 + k];
        float4 wv = w[k];
        acc += hv.x * wv.x + hv.y * wv.y + hv.z * wv.z + hv.w * wv.w;
    }
    const float val = acc + b_in[p];
    h[(size_t)(row0 + r) * PAi + p]  = val;
    hb[(size_t)(row0 + r) * PAi + p] = f2bf(val);
}

// -------- Kernel 2: t[b,j,o,q] = sum_p h[b,j,p] * W_out[o, p*32+q]  (bf16 out) --------
#define RMID 16
__global__ __launch_bounds__(256) void k_mid(const float* __restrict__ h,
                                             const float* __restrict__ W_out,
                                             ushort* __restrict__ t) {
    __shared__ __attribute__((aligned(16))) float hst[PAi][RMID];
    const int tid  = threadIdx.x;
    const int row0 = blockIdx.x * RMID;
    for (int s = tid; s < RMID * PAi; s += 256) {
        const int r = s >> 5, p = s & 31;
        hst[p][r] = h[(size_t)(row0 + r) * PAi + p];
    }
    __syncthreads();
    const int qg = tid & 7;
    const int o1 = tid >> 3;
    const float4* W4 = (const float4*)W_out;
    float4 accA[RMID], accB[RMID];
#pragma unroll
    for (int r = 0; r < RMID; ++r) {
        accA[r] = float4{0, 0, 0, 0};
        accB[r] = float4{0, 0, 0, 0};
    }
#pragma unroll 2
    for (int p = 0; p < PAi; ++p) {
        const float4 wa = W4[(o1 * PAi + p) * 8 + qg];
        const float4 wb = W4[((o1 + 32) * PAi + p) * 8 + qg];
#pragma unroll
        for (int r4 = 0; r4 < RMID / 4; ++r4) {
            const float4 h4 = *(const float4*)&hst[p][r4 * 4];
            const float hr[4] = {h4.x, h4.y, h4.z, h4.w};
#pragma unroll
            for (int e = 0; e < 4; ++e) {
                const int r = r4 * 4 + e;
                accA[r].x += hr[e] * wa.x; accA[r].y += hr[e] * wa.y;
                accA[r].z += hr[e] * wa.z; accA[r].w += hr[e] * wa.w;
                accB[r].x += hr[e] * wb.x; accB[r].y += hr[e] * wb.y;
                accB[r].z += hr[e] * wb.z; accB[r].w += hr[e] * wb.w;
            }
        }
    }
#pragma unroll
    for (int r = 0; r < RMID; ++r) {
        ushort4 ua, ub;
        ua.x = f2bf(accA[r].x); ua.y = f2bf(accA[r].y); ua.z = f2bf(accA[r].z); ua.w = f2bf(accA[r].w);
        ub.x = f2bf(accB[r].x); ub.y = f2bf(accB[r].y); ub.z = f2bf(accB[r].z); ub.w = f2bf(accB[r].w);
        ushort* dst = t + (size_t)(row0 + r) * OO * PAi;
        *(ushort4*)(dst + (o1 * 8 + qg) * 4)        = ua;
        *(ushort4*)(dst + ((o1 + 32) * 8 + qg) * 4) = ub;
    }
}

// -------- Kernel 3: MFMA + 3-stage double-buffered LDS-transpose pipeline --------
// Per chunk k (256 jo): A(k)=issue {4 t-frag + 4 pw} loads into regs; B(k)=MFMA(t-frags
// loaded one chunk earlier) -> LDS; C(k)=LDS-read i-rows + add pw + 1KB-coalesced NT store.
// Iteration: C(k) | A(k+2) | B(k+1) | barrier  -> MFMA never waits on a fresh load; every
// iteration issues 8 loads + 4 stores with no dependent stall in front.
#define SEG 4096
#define CH  256
#define NCH (SEG / CH)
#define LSTR 260
__global__ __launch_bounds__(256, 4) void k_out(const ushort* __restrict__ t,   // bf16 [B][L*OO][PAi]
                                                const ushort* __restrict__ hb,  // bf16 [B][L][PAi]
                                                const float* __restrict__ pw,
                                                const float* __restrict__ b_out,
                                                float* __restrict__ out) {
    __shared__ float sacc0[16 * LSTR];  // 16.6 KB
    __shared__ float sacc1[16 * LSTR];
    const int tid  = threadIdx.x;
    const int lane = tid & 63;
    const int wave = tid >> 6;
    const int b    = blockIdx.z;
    const int i0   = blockIdx.y * 16;
    const int seg0 = blockIdx.x * SEG;
    const int l15  = lane & 15;
    const int g    = lane >> 4;

    const bf16x8 hfrag = *(const bf16x8*)(hb + ((size_t)(b * LL + i0 + l15)) * PAi + g * 8);
    const f32x4 bo4 = *(const f32x4*)(b_out + ((lane * 4) & 63));
    const size_t outrow0 = ((size_t)(b * LL + i0)) * (LL * OO);

    // A: issue loads for chunk c into (tf, pv)
    auto loadA = [&](int c, bf16x8* tf, f32x4* pv) {
        const int cbase = seg0 + c * CH;
#pragma unroll
        for (int rr = 0; rr < 4; ++rr)
            pv[rr] = *(const f32x4*)(pw + outrow0 + (size_t)(wave * 4 + rr) * (LL * OO) + cbase + lane * 4);
        const ushort* tb0 = t + ((size_t)b * LL * OO + cbase + wave * 64 + l15) * PAi + g * 8;
#pragma unroll
        for (int tt = 0; tt < 4; ++tt)
            tf[tt] = *(const bf16x8*)(tb0 + (size_t)tt * (16 * PAi));
    };
    // B: MFMA tf -> sbuf
    auto mfmaB = [&](const bf16x8* tf, float* sbuf) {
#pragma unroll
        for (int tt = 0; tt < 4; ++tt) {
            f32x4 z = {0.f, 0.f, 0.f, 0.f};
            f32x4 a = __builtin_amdgcn_mfma_f32_16x16x32_bf16(tf[tt], hfrag, z, 0, 0, 0);
            *(f32x4*)&sbuf[l15 * LSTR + wave * 64 + tt * 16 + g * 4] = a;
        }
    };
    // C: LDS rows + pw + bias -> NT store
    auto consC = [&](int c, const f32x4* pv, const float* sbuf) {
        const int cbase = seg0 + c * CH;
#pragma unroll
        for (int rr = 0; rr < 4; ++rr) {
            const int row = wave * 4 + rr;
            const f32x4 a4 = *(const f32x4*)&sbuf[row * LSTR + lane * 4];
            f32x4 res = a4 + bo4 + pv[rr];
            __builtin_nontemporal_store(res,
                (f32x4*)(out + outrow0 + (size_t)row * (LL * OO) + cbase + lane * 4));
        }
    };

    bf16x8 tf0[4], tf1[4];
    f32x4  pv0[4], pv1[4];

    loadA(0, tf0, pv0);
    loadA(1, tf1, pv1);
    mfmaB(tf0, sacc0);
    __syncthreads();

    for (int c = 0; c < NCH; c += 2) {
        // half-iter even: consume c (sacc0/pv0), prefetch c+2 -> set0, MFMA c+1 -> sacc1
        consC(c, pv0, sacc0);
        if (c + 2 < NCH) loadA(c + 2, tf0, pv0);
        if (c + 1 < NCH) mfmaB(tf1, sacc1);
        __syncthreads();
        if (c + 1 >= NCH) break;
        // half-iter odd: consume c+1 (sacc1/pv1), prefetch c+3 -> set1, MFMA c+2 -> sacc0
        consC(c + 1, pv1, sacc1);
        if (c + 3 < NCH) loadA(c + 3, tf1, pv1);
        if (c + 2 < NCH) mfmaB(tf0, sacc0);
        __syncthreads();
    }
}

extern "C" void kernel_launch(void* const* d_in, const int* in_sizes, int n_in,
                              void* d_out, int out_size, void* d_ws, size_t ws_size,
                              hipStream_t stream) {
    const float* hidden = (const float*)d_in[0];
    const float* pw     = (const float*)d_in[1];
    const float* W_in   = (const float*)d_in[2];
    const float* b_in   = (const float*)d_in[3];
    const float* W_out  = (const float*)d_in[4];
    const float* b_out  = (const float*)d_in[5];
    float* out = (float*)d_out;

    float*  h  = (float*)d_ws;                                // 65536 f32  (256 KB)
    ushort* hb = (ushort*)(h + (size_t)BB * LL * PAi);        // 65536 bf16 (128 KB)
    ushort* tb = hb + (size_t)BB * LL * PAi;                  // 4194304 bf16 (8 MB)

    k_in <<<dim3(BB * LL / 8), 256, 0, stream>>>(hidden, W_in, b_in, h, hb);
    k_mid<<<dim3(BB * LL / RMID), 256, 0, stream>>>(h, W_out, tb);
    // 8 jo-segments x 32 i-tiles x B = 1024 blocks = exactly 4/CU resident
    k_out<<<dim3(LL * OO / SEG, LL / 16, BB), 256, 0, stream>>>(tb, hb, pw, b_out, out);
}